// Round 1
// baseline (127.562 us; speedup 1.0000x reference)
//
#include <hip/hip_runtime.h>

// Varifold loss: kxx + kyy - 2*kxy, each term = sum_{i,j} exp(-||xa_i-xb_j||^2) * (na_i.nb_j)^2
// B=4, N=4096, fp32 in/out (scalar out).

#define NPTS 4096
#define BATCH 4
#define TILE_J 256
#define MI 4                      // i-points per thread
#define I_PER_BLOCK (256 * MI)    // 1024
#define NUM_IBLK (NPTS / I_PER_BLOCK)   // 4
#define NUM_JCHUNK (NPTS / TILE_J)      // 16
#define GRID_MAIN (3 * BATCH * NUM_IBLK * NUM_JCHUNK)  // 768

__global__ void vf_init(double* acc) {
    if (threadIdx.x == 0 && blockIdx.x == 0) acc[0] = 0.0;
}

__global__ __launch_bounds__(256, 4)
void vf_pairs(const float* __restrict__ xyz1, const float* __restrict__ xyz2,
              const float* __restrict__ nor1, const float* __restrict__ nor2,
              double* __restrict__ acc) {
    int blk = blockIdx.x;
    int jc = blk % NUM_JCHUNK; blk /= NUM_JCHUNK;
    int ib = blk % NUM_IBLK;   blk /= NUM_IBLK;
    int b  = blk % BATCH;      blk /= BATCH;
    int term = blk;  // 0: xx, 1: yy, 2: xy

    const float *xa, *xb, *na, *nb;
    float w;
    if (term == 0)      { xa = xyz1; xb = xyz1; na = nor1; nb = nor1; w =  1.0f; }
    else if (term == 1) { xa = xyz2; xb = xyz2; na = nor2; nb = nor2; w =  1.0f; }
    else                { xa = xyz1; xb = xyz2; na = nor1; nb = nor2; w = -2.0f; }

    const size_t boff = (size_t)b * NPTS * 3;
    const float* xaB = xa + boff;
    const float* naB = na + boff;
    const float* xbB = xb + boff;
    const float* nbB = nb + boff;

    const int tid = threadIdx.x;

    // Register-resident i-points (4 per thread).
    float xi[MI][3], ni[MI][3];
#pragma unroll
    for (int k = 0; k < MI; ++k) {
        int i = ib * I_PER_BLOCK + k * 256 + tid;
        xi[k][0] = xaB[i * 3 + 0];
        xi[k][1] = xaB[i * 3 + 1];
        xi[k][2] = xaB[i * 3 + 2];
        ni[k][0] = naB[i * 3 + 0];
        ni[k][1] = naB[i * 3 + 1];
        ni[k][2] = naB[i * 3 + 2];
    }

    // Stage 256 j-points into LDS, padded to 8 floats for float4 broadcast reads.
    __shared__ float tile[TILE_J][8];
    {
        int j = jc * TILE_J + tid;
        tile[tid][0] = xbB[j * 3 + 0];
        tile[tid][1] = xbB[j * 3 + 1];
        tile[tid][2] = xbB[j * 3 + 2];
        tile[tid][3] = nbB[j * 3 + 0];
        tile[tid][4] = nbB[j * 3 + 1];
        tile[tid][5] = nbB[j * 3 + 2];
        tile[tid][6] = 0.0f;
        tile[tid][7] = 0.0f;
    }
    __syncthreads();

    float part[MI];
#pragma unroll
    for (int k = 0; k < MI; ++k) part[k] = 0.0f;

#pragma unroll 4
    for (int jj = 0; jj < TILE_J; ++jj) {
        // All lanes read the same LDS address -> broadcast, conflict-free.
        float4 p = *reinterpret_cast<const float4*>(&tile[jj][0]);
        float4 q = *reinterpret_cast<const float4*>(&tile[jj][4]);
        float xj0 = p.x, xj1 = p.y, xj2 = p.z;
        float nj0 = p.w, nj1 = q.x, nj2 = q.y;
#pragma unroll
        for (int k = 0; k < MI; ++k) {
            float dx = xi[k][0] - xj0;
            float dy = xi[k][1] - xj1;
            float dz = xi[k][2] - xj2;
            float s  = fmaf(dz, dz, fmaf(dy, dy, dx * dx));
            float d  = fmaf(ni[k][2], nj2, fmaf(ni[k][1], nj1, ni[k][0] * nj0));
            float e  = __expf(-s);           // v_mul(log2e) + v_exp_f32
            part[k]  = fmaf(e, d * d, part[k]);
        }
    }

    float sum = (part[0] + part[1]) + (part[2] + part[3]);
    sum *= w;

    // Wave (64-lane) shuffle reduction.
#pragma unroll
    for (int off = 32; off > 0; off >>= 1)
        sum += __shfl_down(sum, off, 64);

    __shared__ float wsum[4];
    int wave = tid >> 6;
    if ((tid & 63) == 0) wsum[wave] = sum;
    __syncthreads();
    if (tid == 0) {
        double s = ((double)wsum[0] + (double)wsum[1]) +
                   ((double)wsum[2] + (double)wsum[3]);
        atomicAdd(acc, s);
    }
}

__global__ void vf_finalize(const double* __restrict__ acc, float* __restrict__ out) {
    if (threadIdx.x == 0 && blockIdx.x == 0) out[0] = (float)acc[0];
}

extern "C" void kernel_launch(void* const* d_in, const int* in_sizes, int n_in,
                              void* d_out, int out_size, void* d_ws, size_t ws_size,
                              hipStream_t stream) {
    const float* xyz1 = (const float*)d_in[0];
    const float* xyz2 = (const float*)d_in[1];
    const float* nor1 = (const float*)d_in[2];
    const float* nor2 = (const float*)d_in[3];
    float* out = (float*)d_out;
    double* acc = (double*)d_ws;   // d_ws is poisoned each call -> zero it ourselves

    vf_init<<<1, 64, 0, stream>>>(acc);
    vf_pairs<<<GRID_MAIN, 256, 0, stream>>>(xyz1, xyz2, nor1, nor2, acc);
    vf_finalize<<<1, 64, 0, stream>>>(acc, out);
}

// Round 3
// 108.402 us; speedup vs baseline: 1.1767x; 1.1767x over previous
//
#include <hip/hip_runtime.h>

// Varifold loss kxx + kyy - 2*kxy via MFMA.
// S_ij = |xi|^2 + |xj|^2 - 2 xi.xj  and  D_ij = ni.nj  are computed as
// augmented bf16 dot products with mfma_f32_16x16x32_bf16 (K=32, k<16 used).
// Every input value is hi/lo bf16-split across spare K slots (~fp24 precision).
// Sum is layout-insensitive: we exp+square+reduce every acc element.

typedef short bf16x8 __attribute__((ext_vector_type(8)));
typedef float f32x4 __attribute__((ext_vector_type(4)));

#define NPTS 4096
#define BATCH 4
#define IBLK 256                  // i-points per block
#define JCHUNK 512                // j-points staged per block
#define NIB (NPTS / IBLK)         // 16
#define NJC (NPTS / JCHUNK)       // 8
#define GRID (3 * BATCH * NIB * NJC)  // 1536

static __device__ __forceinline__ short f2bf(float f) {
    unsigned u = __builtin_bit_cast(unsigned, f);
    unsigned r = u + 0x7fffu + ((u >> 16) & 1u);   // RNE
    return (short)(r >> 16);
}

// v -> h (exact bf16 value as float) + l (residual)
static __device__ __forceinline__ void split(float v, float& h, float& l) {
    unsigned u = __builtin_bit_cast(unsigned, v);
    unsigned rb = (u + 0x7fffu + ((u >> 16) & 1u)) & 0xffff0000u;
    h = __builtin_bit_cast(float, rb);
    l = v - h;
}

static __device__ __forceinline__ void enc_store(short* dst, const float* f) {
    bf16x8 v0, v1;
#pragma unroll
    for (int k = 0; k < 8; ++k) v0[k] = f2bf(f[k]);
#pragma unroll
    for (int k = 0; k < 8; ++k) v1[k] = f2bf(f[k + 8]);
    *(bf16x8*)(dst) = v0;
    *(bf16x8*)(dst + 8) = v1;
}

__global__ __launch_bounds__(256)
void vf_main(const float* __restrict__ xyz1, const float* __restrict__ xyz2,
             const float* __restrict__ nor1, const float* __restrict__ nor2,
             float* __restrict__ out)
{
    // rows of 16 shorts (32 B); +1 zero row each for MFMA quads 2-3
    __shared__ short sAS[(IBLK + 1) * 16];
    __shared__ short sAD[(IBLK + 1) * 16];
    __shared__ short sBS[(JCHUNK + 1) * 16];
    __shared__ short sBD[(JCHUNK + 1) * 16];

    int blk = blockIdx.x;
    int term = blk % 3; int r = blk / 3;   // term fastest: interleaves +/- atomics
    int b  = r & 3;  r >>= 2;
    int ib = r & 15; r >>= 4;
    int jc = r;                             // 0..7

    const float *pa, *na, *pb, *nb; float w;
    if (term == 0)      { pa = xyz1; na = nor1; pb = xyz1; nb = nor1; w =  1.f; }
    else if (term == 1) { pa = xyz2; na = nor2; pb = xyz2; nb = nor2; w =  1.f; }
    else                { pa = xyz1; na = nor1; pb = xyz2; nb = nor2; w = -2.f; }
    size_t boff = (size_t)b * NPTS * 3;
    pa += boff; na += boff; pb += boff; nb += boff;

    const int tid = threadIdx.x;

    // ---- stage i-side (A-operand) encodings: 256 points, 1 per thread ----
    {
        int i = ib * IBLK + tid;
        float x0 = pa[i*3+0], x1 = pa[i*3+1], x2 = pa[i*3+2];
        float n0 = na[i*3+0], n1 = na[i*3+1], n2 = na[i*3+2];
        float s2 = fmaf(x2, x2, fmaf(x1, x1, x0 * x0));
        float sh, sl, xh0, xl0, xh1, xl1, xh2, xl2;
        split(s2, sh, sl); split(x0, xh0, xl0); split(x1, xh1, xl1); split(x2, xh2, xl2);
        float nh0, nl0, nh1, nl1, nh2, nl2;
        split(n0, nh0, nl0); split(n1, nh1, nl1); split(n2, nh2, nl2);
        float aS[16] = { sh, sl, 1.f, 1.f,
                         -2.f*xh0, -2.f*xh0, -2.f*xl0,
                         -2.f*xh1, -2.f*xh1, -2.f*xl1,
                         -2.f*xh2, -2.f*xh2, -2.f*xl2, 0.f, 0.f, 0.f };
        float aD[16] = { nh0, nh0, nl0, nh1, nh1, nl1, nh2, nh2, nl2,
                         0.f, 0.f, 0.f, 0.f, 0.f, 0.f, 0.f };
        enc_store(&sAS[tid * 16], aS);
        enc_store(&sAD[tid * 16], aD);
    }
    // ---- stage j-side (B-operand) encodings: 512 points, 2 per thread ----
#pragma unroll
    for (int k2 = 0; k2 < 2; ++k2) {
        int jl = tid + k2 * 256;
        int j = jc * JCHUNK + jl;
        float x0 = pb[j*3+0], x1 = pb[j*3+1], x2 = pb[j*3+2];
        float n0 = nb[j*3+0], n1 = nb[j*3+1], n2 = nb[j*3+2];
        float s2 = fmaf(x2, x2, fmaf(x1, x1, x0 * x0));
        float sh, sl, xh0, xl0, xh1, xl1, xh2, xl2;
        split(s2, sh, sl); split(x0, xh0, xl0); split(x1, xh1, xl1); split(x2, xh2, xl2);
        float nh0, nl0, nh1, nl1, nh2, nl2;
        split(n0, nh0, nl0); split(n1, nh1, nl1); split(n2, nh2, nl2);
        // pairing: a[k]*b[k] -> hh, hl, lh per dim
        float bS[16] = { 1.f, 1.f, sh, sl,
                         xh0, xl0, xh0,
                         xh1, xl1, xh1,
                         xh2, xl2, xh2, 0.f, 0.f, 0.f };
        float bD[16] = { nh0, nl0, nh0, nh1, nl1, nh1, nh2, nl2, nh2,
                         0.f, 0.f, 0.f, 0.f, 0.f, 0.f, 0.f };
        enc_store(&sBS[jl * 16], bS);
        enc_store(&sBD[jl * 16], bD);
    }
    if (tid == 0) {
#pragma unroll
        for (int k = 0; k < 16; ++k) {
            sAS[IBLK * 16 + k] = 0;  sAD[IBLK * 16 + k] = 0;
            sBS[JCHUNK * 16 + k] = 0; sBD[JCHUNK * 16 + k] = 0;
        }
    }
    __syncthreads();

    const int lane = tid & 63;
    const int wv = tid >> 6;       // wave id 0..3
    const int m = lane & 15;       // row/col within 16x16 tile
    const int q = lane >> 4;       // k-quad 0..3; quads 0,1 carry k 0..15
    const int qh = q & 1;
    const bool qlive = (q < 2);

    // A fragments: 4 i-tiles of 16 rows, resident in VGPRs
    bf16x8 AS[4], AD[4];
#pragma unroll
    for (int t = 0; t < 4; ++t) {
        int ra = qlive ? (wv * 64 + t * 16 + m) : IBLK;
        AS[t] = *(const bf16x8*)&sAS[ra * 16 + qh * 8];
        AD[t] = *(const bf16x8*)&sAD[ra * 16 + qh * 8];
    }

    const f32x4 z4 = {0.f, 0.f, 0.f, 0.f};
    float part = 0.f;

    for (int jt = 0; jt < JCHUNK / 16; ++jt) {
        int rb = qlive ? (jt * 16 + m) : JCHUNK;
        bf16x8 BS = *(const bf16x8*)&sBS[rb * 16 + qh * 8];
        bf16x8 BD = *(const bf16x8*)&sBD[rb * 16 + qh * 8];

        f32x4 accS[4], accD[4];
#pragma unroll
        for (int t = 0; t < 4; ++t) {
            accS[t] = __builtin_amdgcn_mfma_f32_16x16x32_bf16(AS[t], BS, z4, 0, 0, 0);
            accD[t] = __builtin_amdgcn_mfma_f32_16x16x32_bf16(AD[t], BD, z4, 0, 0, 0);
        }
#pragma unroll
        for (int t = 0; t < 4; ++t) {
#pragma unroll
            for (int e = 0; e < 4; ++e) {
                float s = accS[t][e];
                float d = accD[t][e];
                // e^{-S} = 2^{-S*log2(e)} via raw v_exp_f32
                float ex = __builtin_amdgcn_exp2f(s * -1.4426950408889634f);
                part = fmaf(ex, d * d, part);
            }
        }
    }

    // wave reduce (64 lanes), then block reduce, one float atomic per block
#pragma unroll
    for (int off = 32; off > 0; off >>= 1)
        part += __shfl_down(part, off, 64);

    __shared__ float wsum[4];
    if (lane == 0) wsum[wv] = part;
    __syncthreads();
    if (tid == 0) {
        double s = ((double)wsum[0] + (double)wsum[1]) +
                   ((double)wsum[2] + (double)wsum[3]);
        atomicAdd(out, (float)(s * (double)w));
    }
}

extern "C" void kernel_launch(void* const* d_in, const int* in_sizes, int n_in,
                              void* d_out, int out_size, void* d_ws, size_t ws_size,
                              hipStream_t stream) {
    const float* xyz1 = (const float*)d_in[0];
    const float* xyz2 = (const float*)d_in[1];
    const float* nor1 = (const float*)d_in[2];
    const float* nor2 = (const float*)d_in[3];
    float* out = (float*)d_out;

    (void)hipMemsetAsync(out, 0, sizeof(float), stream);   // d_out re-poisoned each call
    vf_main<<<GRID, 256, 0, stream>>>(xyz1, xyz2, nor1, nor2, out);
}

// Round 4
// 107.808 us; speedup vs baseline: 1.1832x; 1.0055x over previous
//
#include <hip/hip_runtime.h>

// Varifold loss kxx + kyy - 2*kxy via mfma_f32_32x32x16_bf16.
// accS directly accumulates -log2(e)*S_ij (scale folded into encodings), so
// epilogue per pair is exactly: exp2(accS) * accD^2, fma into partial.
// Inputs hi/lo bf16-split across K slots (13 used for S, 9 for D) -> ~fp24.
// A-fragments built per-lane from global (no LDS); B staged in LDS (32 KB).

typedef short bf16x8 __attribute__((ext_vector_type(8)));
typedef float f32x16 __attribute__((ext_vector_type(16)));

#define NPTS 4096
#define BATCH 4
#define IBLK 128                   // 4 waves x one 32-row i-tile each
#define JCHUNK 512                 // 16 j-tiles of 32
#define NIB (NPTS / IBLK)          // 32
#define NJC (NPTS / JCHUNK)        // 8
#define GRID (3 * BATCH * NIB * NJC)   // 3072
#define LOG2E 1.4426950408889634f

static __device__ __forceinline__ short f2bf(float f) {
    unsigned u = __builtin_bit_cast(unsigned, f);
    unsigned r = u + 0x7fffu + ((u >> 16) & 1u);   // RNE
    return (short)(r >> 16);
}
// v -> h (exact bf16 value) + l (residual)
static __device__ __forceinline__ void split(float v, float& h, float& l) {
    unsigned u = __builtin_bit_cast(unsigned, v);
    unsigned rb = (u + 0x7fffu + ((u >> 16) & 1u)) & 0xffff0000u;
    h = __builtin_bit_cast(float, rb);
    l = v - h;
}

// i-side: accS slot pairing (A,B): (gh,1)(gl,1)(1,gh')(1,gl') then per dim
// (uh,vh)(uh,vl)(ul,vh) with u = 2*log2e*xi, v = xj, g = -log2e*|x|^2.
static __device__ __forceinline__ void encodeA(float x0, float x1, float x2,
                                               float n0, float n1, float n2,
                                               float fS[16], float fD[16]) {
    float s2 = fmaf(x2, x2, fmaf(x1, x1, x0 * x0));
    float gh, gl; split(-LOG2E * s2, gh, gl);
    float u0h,u0l,u1h,u1l,u2h,u2l;
    split(2.f*LOG2E*x0, u0h, u0l);
    split(2.f*LOG2E*x1, u1h, u1l);
    split(2.f*LOG2E*x2, u2h, u2l);
    fS[0]=gh;  fS[1]=gl;  fS[2]=1.f; fS[3]=1.f;
    fS[4]=u0h; fS[5]=u0h; fS[6]=u0l;
    fS[7]=u1h; fS[8]=u1h; fS[9]=u1l;
    fS[10]=u2h; fS[11]=u2h; fS[12]=u2l;
    fS[13]=0.f; fS[14]=0.f; fS[15]=0.f;
    float m0h,m0l,m1h,m1l,m2h,m2l;
    split(n0, m0h, m0l); split(n1, m1h, m1l); split(n2, m2h, m2l);
    fD[0]=m0h; fD[1]=m0h; fD[2]=m0l;
    fD[3]=m1h; fD[4]=m1h; fD[5]=m1l;
    fD[6]=m2h; fD[7]=m2h; fD[8]=m2l;
#pragma unroll
    for (int k = 9; k < 16; ++k) fD[k] = 0.f;
}

static __device__ __forceinline__ void encodeB(float x0, float x1, float x2,
                                               float n0, float n1, float n2,
                                               float fS[16], float fD[16]) {
    float s2 = fmaf(x2, x2, fmaf(x1, x1, x0 * x0));
    float gh, gl; split(-LOG2E * s2, gh, gl);
    float v0h,v0l,v1h,v1l,v2h,v2l;
    split(x0, v0h, v0l); split(x1, v1h, v1l); split(x2, v2h, v2l);
    fS[0]=1.f; fS[1]=1.f; fS[2]=gh;  fS[3]=gl;
    fS[4]=v0h; fS[5]=v0l; fS[6]=v0h;
    fS[7]=v1h; fS[8]=v1l; fS[9]=v1h;
    fS[10]=v2h; fS[11]=v2l; fS[12]=v2h;
    fS[13]=0.f; fS[14]=0.f; fS[15]=0.f;
    float m0h,m0l,m1h,m1l,m2h,m2l;
    split(n0, m0h, m0l); split(n1, m1h, m1l); split(n2, m2h, m2l);
    fD[0]=m0h; fD[1]=m0l; fD[2]=m0h;
    fD[3]=m1h; fD[4]=m1l; fD[5]=m1h;
    fD[6]=m2h; fD[7]=m2l; fD[8]=m2h;
#pragma unroll
    for (int k = 9; k < 16; ++k) fD[k] = 0.f;
}

static __device__ __forceinline__ void store16(short* dst, const float f[16]) {
    bf16x8 a, b;
#pragma unroll
    for (int k = 0; k < 8; ++k) { a[k] = f2bf(f[k]); b[k] = f2bf(f[k + 8]); }
    *(bf16x8*)dst = a;
    *(bf16x8*)(dst + 8) = b;
}

__global__ __launch_bounds__(256)
void vf_main(const float* __restrict__ xyz1, const float* __restrict__ xyz2,
             const float* __restrict__ nor1, const float* __restrict__ nor2,
             float* __restrict__ out)
{
    __shared__ short sBS[JCHUNK * 16];   // 16 KB
    __shared__ short sBD[JCHUNK * 16];   // 16 KB

    int blk = blockIdx.x;
    int term = blk % 3; int r = blk / 3;   // term fastest: +/- atomics interleave
    int b  = r & 3;  r >>= 2;
    int ib = r & 31; r >>= 5;
    int jc = r;                             // 0..7

    const float *pa, *na, *pb, *nb; float w;
    if (term == 0)      { pa = xyz1; na = nor1; pb = xyz1; nb = nor1; w =  1.f; }
    else if (term == 1) { pa = xyz2; na = nor2; pb = xyz2; nb = nor2; w =  1.f; }
    else                { pa = xyz1; na = nor1; pb = xyz2; nb = nor2; w = -2.f; }
    size_t boff = (size_t)b * NPTS * 3;
    pa += boff; na += boff; pb += boff; nb += boff;

    const int tid  = threadIdx.x;
    const int lane = tid & 63;
    const int wv   = tid >> 6;
    const int col  = lane & 31;   // row/col within 32x32 tile
    const int h    = lane >> 5;   // k-half: k = h*8 + j

    // ---- stage B (j-side): 512 points, 2 per thread, into LDS ----
#pragma unroll
    for (int k2 = 0; k2 < 2; ++k2) {
        int jl = tid + k2 * 256;
        int j = jc * JCHUNK + jl;
        float fS[16], fD[16];
        encodeB(pb[j*3+0], pb[j*3+1], pb[j*3+2],
                nb[j*3+0], nb[j*3+1], nb[j*3+2], fS, fD);
        store16(&sBS[jl * 16], fS);
        store16(&sBD[jl * 16], fD);
    }

    // ---- build A fragments per-lane (row = col, k-half = h), no LDS ----
    bf16x8 AS, AD;
    {
        int i = ib * IBLK + wv * 32 + col;
        float fS[16], fD[16];
        encodeA(pa[i*3+0], pa[i*3+1], pa[i*3+2],
                na[i*3+0], na[i*3+1], na[i*3+2], fS, fD);
        bf16x8 sLo, sHi, dLo, dHi;
#pragma unroll
        for (int k = 0; k < 8; ++k) {
            sLo[k] = f2bf(fS[k]); sHi[k] = f2bf(fS[k + 8]);
            dLo[k] = f2bf(fD[k]); dHi[k] = f2bf(fD[k + 8]);
        }
        AS = h ? sHi : sLo;
        AD = h ? dHi : dLo;
    }
    __syncthreads();

    f32x16 z;
#pragma unroll
    for (int k = 0; k < 16; ++k) z[k] = 0.f;

    float part = 0.f;
    const int rbase = col * 16 + h * 8;

    bf16x8 BS = *(const bf16x8*)&sBS[rbase];
    bf16x8 BD = *(const bf16x8*)&sBD[rbase];

    for (int jt = 0; jt < 16; ++jt) {
        int nxt = ((jt + 1) & 15) * (32 * 16) + rbase;   // prefetch next j-tile
        bf16x8 nBS = *(const bf16x8*)&sBS[nxt];
        bf16x8 nBD = *(const bf16x8*)&sBD[nxt];

        f32x16 aS = __builtin_amdgcn_mfma_f32_32x32x16_bf16(AS, BS, z, 0, 0, 0);
        f32x16 aD = __builtin_amdgcn_mfma_f32_32x32x16_bf16(AD, BD, z, 0, 0, 0);

#pragma unroll
        for (int e = 0; e < 16; ++e) {
            float ex = __builtin_amdgcn_exp2f(aS[e]);   // accS == -log2e*S already
            float d  = aD[e];
            part = fmaf(ex, d * d, part);
        }
        BS = nBS; BD = nBD;
    }

    // wave reduce, block reduce, one float atomic per block
#pragma unroll
    for (int off = 32; off > 0; off >>= 1)
        part += __shfl_down(part, off, 64);

    __shared__ float wsum[4];
    if (lane == 0) wsum[wv] = part;
    __syncthreads();
    if (tid == 0) {
        double s = ((double)wsum[0] + (double)wsum[1]) +
                   ((double)wsum[2] + (double)wsum[3]);
        atomicAdd(out, (float)(s * (double)w));
    }
}

extern "C" void kernel_launch(void* const* d_in, const int* in_sizes, int n_in,
                              void* d_out, int out_size, void* d_ws, size_t ws_size,
                              hipStream_t stream) {
    const float* xyz1 = (const float*)d_in[0];
    const float* xyz2 = (const float*)d_in[1];
    const float* nor1 = (const float*)d_in[2];
    const float* nor2 = (const float*)d_in[3];
    float* out = (float*)d_out;

    (void)hipMemsetAsync(out, 0, sizeof(float), stream);   // d_out re-poisoned each call
    vf_main<<<GRID, 256, 0, stream>>>(xyz1, xyz2, nor1, nor2, out);
}